// Round 5
// baseline (157.044 us; speedup 1.0000x reference)
//
#include <hip/hip_runtime.h>
#include <hip/hip_bf16.h>

#define HW_TOTAL 16384
#define C2 128
#define PPB 16
#define NBLK (HW_TOTAL / PPB)

typedef short bf16x8 __attribute__((ext_vector_type(8)));
typedef float f32x4 __attribute__((ext_vector_type(4)));

__device__ __forceinline__ unsigned pk2bf(float lo, float hi) {
    __hip_bfloat162 h = __float22bfloat162_rn(make_float2(lo, hi));
    union { __hip_bfloat162 h; unsigned u; } v; v.h = h;
    return v.u;
}
__device__ __forceinline__ unsigned short f2bf(float f) {
    union { float f; unsigned u; } v; v.f = f;
    unsigned r = v.u + 0x7FFFu + ((v.u >> 16) & 1u);
    return (unsigned short)(r >> 16);
}
__device__ __forceinline__ float fast_sigmoid(float x) {
    return __builtin_amdgcn_rcpf(1.0f + __expf(-x));
}
__device__ __forceinline__ float fast_softplus(float x) {
    return fmaxf(x, 0.0f) + __logf(1.0f + __expf(-fabsf(x)));
}

// ---- Kernel 1: separable DFT of padded 7x7 kernels -> field[hw][c] = (Ar,Ai,0.1*Br,0.1*Bi) ----
__global__ void field_kernel(const float* __restrict__ Ark, const float* __restrict__ Aik,
                             const float* __restrict__ Brk, const float* __restrict__ Bik,
                             float4* __restrict__ field) {
    __shared__ float2 tw[128];
    __shared__ float2 G[2][64][9];
    const int v = blockIdx.x >> 1;
    const int uhalf = blockIdx.x & 1;
    const int t = threadIdx.x;
    if (t < 128) {
        float ph = (float)t * (6.283185307179586f / 128.0f);
        tw[t] = make_float2(cosf(ph), sinf(ph));
    }
    __syncthreads();
    for (int e = t; e < 896; e += 256) {
        const int kern = (e >= 448) ? 1 : 0;
        const int rem = e - kern * 448;
        const int c = rem / 7, p = rem % 7;
        const float* kr = kern ? Brk : Ark;
        const float* ki = kern ? Bik : Aik;
        float gr = 0.f, gi = 0.f;
#pragma unroll
        for (int q = 0; q < 7; ++q) {
            const int idx = (v * (q + 60)) & 127;
            const float twr = tw[idx].x, twi = -tw[idx].y;
            const float ar = kr[c * 49 + p * 7 + q], ai = ki[c * 49 + p * 7 + q];
            gr += ar * twr - ai * twi;
            gi += ar * twi + ai * twr;
        }
        G[kern][c][p] = make_float2(gr, gi);
    }
    __syncthreads();
    const int c = t & 63, ug = t >> 6;
    float2 gA[7], gB[7];
#pragma unroll
    for (int p = 0; p < 7; ++p) { gA[p] = G[0][c][p]; gB[p] = G[1][c][p]; }
    for (int k = 0; k < 16; ++k) {
        const int u = uhalf * 64 + ug * 16 + k;
        float Are = 0.f, Aim = 0.f, Bre = 0.f, Bim = 0.f;
#pragma unroll
        for (int p = 0; p < 7; ++p) {
            const int idx = (u * (p + 60)) & 127;
            const float twr = tw[idx].x, twi = -tw[idx].y;
            Are += gA[p].x * twr - gA[p].y * twi;
            Aim += gA[p].x * twi + gA[p].y * twr;
            Bre += gB[p].x * twr - gB[p].y * twi;
            Bim += gB[p].x * twi + gB[p].y * twr;
        }
        const float mag = sqrtf(Are * Are + Aim * Aim + 1e-8f);
        const float scale = 0.95f * (1.0f / (1.0f + expf(-mag))) / (mag + 1e-8f);
        field[(size_t)(u * 128 + v) * 64 + c] =
            make_float4(Are * scale, Aim * scale, Bre * 0.1f, Bim * 0.1f);
    }
}

// ---- Kernel 2: weights fp32 (k,n) -> bf16 transposed (g,n,k) ----
__global__ void wprep_kernel(const float* __restrict__ Wf, const float* __restrict__ Wi,
                             const float* __restrict__ Wd, ushort* __restrict__ Wt) {
    const int idx = blockIdx.x * 256 + threadIdx.x;
    const int g = idx >> 14;
    const int r = idx & 16383;
    const int n = r >> 7, k = r & 127;
    const float* W = (g == 0) ? Wf : (g == 1) ? Wi : Wd;
    Wt[idx] = f2bf(W[k * 128 + n]);
}

// ---- Kernel 3: barrier-free fused gates-GEMM + complex SSM recurrence ----
__global__ __launch_bounds__(256, 2) void main_kernel(
    const float* __restrict__ x,
    const float* __restrict__ bfv, const float* __restrict__ biv, const float* __restrict__ bdv,
    const float4* __restrict__ field,
    const ushort* __restrict__ Wt,
    float* __restrict__ out)
{
    const int tid  = threadIdx.x;
    const int lane = tid & 63;
    const int wave = tid >> 6;
    const int l15  = lane & 15;
    const int lg   = lane >> 4;

    // persistent weight fragments (registers)
    bf16x8 wf[3][2][4];
#pragma unroll
    for (int g = 0; g < 3; ++g)
#pragma unroll
        for (int s = 0; s < 2; ++s) {
            const int n = l15 + 16 * (wave + 4 * s);
#pragma unroll
            for (int ks = 0; ks < 4; ++ks)
                wf[g][s][ks] = *(const bf16x8*)(Wt + ((g * 128 + n) * 128 + 32 * ks + 8 * lg));
        }

    const int c0 = l15 + 16 * wave;
    const float bia[3][2] = { { bfv[c0] + 2.0f, bfv[c0 + 64] + 2.0f },
                              { biv[c0],        biv[c0 + 64]        },
                              { bdv[c0],        bdv[c0 + 64]        } };

    const int hw0 = blockIdx.x * PPB;

    // running per-thread pointers
    const float* ab = x + ((size_t)l15 * HW_TOTAL + hw0) * C2 + 8 * lg;   // A-frag rows
    const float* rbp[4];
    float* op[4];
#pragma unroll
    for (int r = 0; r < 4; ++r) {
        rbp[r] = x   + ((size_t)(4 * lg + r) * HW_TOTAL + hw0) * C2 + c0;
        op[r]  = out + ((size_t)(4 * lg + r) * HW_TOTAL + hw0) * C2 + c0;
    }
    const float4* fldp = field + (size_t)hw0 * 64 + c0;

    float4 rawA[8], rawB[8];

    auto load_af = [&](float4 (&ra)[8]) {
#pragma unroll
        for (int ks = 0; ks < 4; ++ks) {
            ra[2 * ks]     = *(const float4*)(ab + 32 * ks);
            ra[2 * ks + 1] = *(const float4*)(ab + 32 * ks + 4);
        }
        ab += C2;
    };

    auto compute = [&](const float4 (&ra)[8]) {
        // issue the small loads first; latency hides under cvt+MFMA
        const float4 fld = *fldp; fldp += 64;
        float xr4[4], xi4[4];
#pragma unroll
        for (int r = 0; r < 4; ++r) {
            xr4[r] = rbp[r][0];
            xi4[r] = rbp[r][64];
            rbp[r] += C2;
        }

        // convert A-tile to bf16 fragments
        bf16x8 af[4];
#pragma unroll
        for (int ks = 0; ks < 4; ++ks) {
            union { unsigned u[4]; bf16x8 v; } pk;
            pk.u[0] = pk2bf(ra[2 * ks].x,     ra[2 * ks].y);
            pk.u[1] = pk2bf(ra[2 * ks].z,     ra[2 * ks].w);
            pk.u[2] = pk2bf(ra[2 * ks + 1].x, ra[2 * ks + 1].y);
            pk.u[3] = pk2bf(ra[2 * ks + 1].z, ra[2 * ks + 1].w);
            af[ks] = pk.v;
        }

        // GEMM: 3 gates x 2 halves, K=128, bias in C
        f32x4 acc[3][2];
#pragma unroll
        for (int g = 0; g < 3; ++g)
#pragma unroll
            for (int s = 0; s < 2; ++s) {
                const float b = bia[g][s];
                acc[g][s] = (f32x4){b, b, b, b};
            }
#pragma unroll
        for (int ks = 0; ks < 4; ++ks)
#pragma unroll
            for (int g = 0; g < 3; ++g)
#pragma unroll
                for (int s = 0; s < 2; ++s)
                    acc[g][s] = __builtin_amdgcn_mfma_f32_16x16x32_bf16(
                        af[ks], wf[g][s][ks], acc[g][s], 0, 0, 0);

        // gates + T=16 recurrence (matrix doubling); Br,Bi pre-scaled by 0.1
        const float Ar = fld.x, Ai = fld.y, Br = fld.z, Bi = fld.w;
#pragma unroll
        for (int r = 0; r < 4; ++r) {
            const float fg_r = fast_sigmoid(acc[0][0][r]);
            const float fg_i = fast_sigmoid(acc[0][1][r]);
            const float ig_r = fast_sigmoid(acc[1][0][r]);
            const float ig_i = fast_sigmoid(acc[1][1][r]);
            const float dl_r = fast_softplus(acc[2][0][r]);
            const float dl_i = fast_softplus(acc[2][1][r]);
            float vr = dl_r * ig_r * fmaf(Br, xr4[r], -Bi * xi4[r]);
            float vi = dl_i * ig_i * fmaf(Br, xi4[r],  Bi * xr4[r]);
            float a  = fg_r * Ar, bm = -(fg_r * Ai);
            float cm = fg_i * Ai, d  = fg_i * Ar;
#pragma unroll
            for (int j = 0; j < 4; ++j) {
                const float nvr = fmaf(a, vr, fmaf(bm, vi, vr));
                const float nvi = fmaf(cm, vr, fmaf(d, vi, vi));
                if (j < 3) {
                    const float trc = a + d, bc = bm * cm;
                    const float na = fmaf(a, a, bc), nd = fmaf(d, d, bc);
                    const float nb = bm * trc, nc = cm * trc;
                    a = na; bm = nb; cm = nc; d = nd;
                }
                vr = nvr; vi = nvi;
            }
            op[r][0]  = vr;
            op[r][64] = vi;
            op[r] += C2;
        }
    };

    // 1-deep software pipeline, no barriers anywhere
    load_af(rawA);
    for (int p = 0; p < PPB; p += 2) {
        load_af(rawB);
        compute(rawA);
        if (p + 2 < PPB) load_af(rawA);
        compute(rawB);
    }
}

extern "C" void kernel_launch(void* const* d_in, const int* in_sizes, int n_in,
                              void* d_out, int out_size, void* d_ws, size_t ws_size,
                              hipStream_t stream) {
    const float* x      = (const float*)d_in[0];
    const float* Wf     = (const float*)d_in[1];
    const float* bf     = (const float*)d_in[2];
    const float* Wi     = (const float*)d_in[3];
    const float* bi     = (const float*)d_in[4];
    const float* Wd     = (const float*)d_in[5];
    const float* bd     = (const float*)d_in[6];
    const float* A_real = (const float*)d_in[7];
    const float* A_imag = (const float*)d_in[8];
    const float* B_real = (const float*)d_in[9];
    const float* B_imag = (const float*)d_in[10];

    float4* field = (float4*)d_ws;                                       // 16 MiB
    ushort* Wt = (ushort*)((char*)d_ws + (size_t)HW_TOTAL * 64 * 16);    // 96 KiB

    field_kernel<<<dim3(256), dim3(256), 0, stream>>>(A_real, A_imag, B_real, B_imag, field);
    wprep_kernel<<<dim3(192), dim3(256), 0, stream>>>(Wf, Wi, Wd, Wt);
    main_kernel<<<dim3(NBLK), dim3(256), 0, stream>>>(x, bf, bi, bd, field, Wt, (float*)d_out);
}

// Round 6
// 150.741 us; speedup vs baseline: 1.0418x; 1.0418x over previous
//
#include <hip/hip_runtime.h>
#include <hip/hip_bf16.h>

#define HW_TOTAL 16384
#define C2 128
#define PPB 16
#define NBLK (HW_TOTAL / PPB)

typedef short bf16x8 __attribute__((ext_vector_type(8)));
typedef float f32x4 __attribute__((ext_vector_type(4)));

__device__ __forceinline__ unsigned pk2bf(float lo, float hi) {
    __hip_bfloat162 h = __float22bfloat162_rn(make_float2(lo, hi));
    union { __hip_bfloat162 h; unsigned u; } v; v.h = h;
    return v.u;
}
__device__ __forceinline__ unsigned short f2bf(float f) {
    union { float f; unsigned u; } v; v.f = f;
    unsigned r = v.u + 0x7FFFu + ((v.u >> 16) & 1u);
    return (unsigned short)(r >> 16);
}
__device__ __forceinline__ float fast_sigmoid(float x) {
    return __builtin_amdgcn_rcpf(1.0f + __expf(-x));
}
__device__ __forceinline__ float fast_softplus(float x) {
    return fmaxf(x, 0.0f) + __logf(1.0f + __expf(-fabsf(x)));
}

// ---- Kernel 1: separable DFT of padded 7x7 kernels -> field[hw][c] = (Ar,Ai,0.1*Br,0.1*Bi) ----
__global__ void field_kernel(const float* __restrict__ Ark, const float* __restrict__ Aik,
                             const float* __restrict__ Brk, const float* __restrict__ Bik,
                             float4* __restrict__ field) {
    __shared__ float2 tw[128];
    __shared__ float2 G[2][64][9];
    const int v = blockIdx.x >> 1;
    const int uhalf = blockIdx.x & 1;
    const int t = threadIdx.x;
    if (t < 128) {
        float ph = (float)t * (6.283185307179586f / 128.0f);
        tw[t] = make_float2(cosf(ph), sinf(ph));
    }
    __syncthreads();
    for (int e = t; e < 896; e += 256) {
        const int kern = (e >= 448) ? 1 : 0;
        const int rem = e - kern * 448;
        const int c = rem / 7, p = rem % 7;
        const float* kr = kern ? Brk : Ark;
        const float* ki = kern ? Bik : Aik;
        float gr = 0.f, gi = 0.f;
#pragma unroll
        for (int q = 0; q < 7; ++q) {
            const int idx = (v * (q + 60)) & 127;
            const float twr = tw[idx].x, twi = -tw[idx].y;
            const float ar = kr[c * 49 + p * 7 + q], ai = ki[c * 49 + p * 7 + q];
            gr += ar * twr - ai * twi;
            gi += ar * twi + ai * twr;
        }
        G[kern][c][p] = make_float2(gr, gi);
    }
    __syncthreads();
    const int c = t & 63, ug = t >> 6;
    float2 gA[7], gB[7];
#pragma unroll
    for (int p = 0; p < 7; ++p) { gA[p] = G[0][c][p]; gB[p] = G[1][c][p]; }
    for (int k = 0; k < 16; ++k) {
        const int u = uhalf * 64 + ug * 16 + k;
        float Are = 0.f, Aim = 0.f, Bre = 0.f, Bim = 0.f;
#pragma unroll
        for (int p = 0; p < 7; ++p) {
            const int idx = (u * (p + 60)) & 127;
            const float twr = tw[idx].x, twi = -tw[idx].y;
            Are += gA[p].x * twr - gA[p].y * twi;
            Aim += gA[p].x * twi + gA[p].y * twr;
            Bre += gB[p].x * twr - gB[p].y * twi;
            Bim += gB[p].x * twi + gB[p].y * twr;
        }
        const float mag = sqrtf(Are * Are + Aim * Aim + 1e-8f);
        const float scale = 0.95f * (1.0f / (1.0f + expf(-mag))) / (mag + 1e-8f);
        field[(size_t)(u * 128 + v) * 64 + c] =
            make_float4(Are * scale, Aim * scale, Bre * 0.1f, Bim * 0.1f);
    }
}

// ---- Kernel 2: weights fp32 (k,n) -> bf16 transposed (g,n,k) ----
__global__ void wprep_kernel(const float* __restrict__ Wf, const float* __restrict__ Wi,
                             const float* __restrict__ Wd, ushort* __restrict__ Wt) {
    const int idx = blockIdx.x * 256 + threadIdx.x;
    const int g = idx >> 14;
    const int r = idx & 16383;
    const int n = r >> 7, k = r & 127;
    const float* W = (g == 0) ? Wf : (g == 1) ? Wi : Wd;
    Wt[idx] = f2bf(W[k * 128 + n]);
}

// ---- Kernel 3: barrier-free, fully register-prefetched pipeline ----
__global__ __launch_bounds__(256, 2) void main_kernel(
    const float* __restrict__ x,
    const float* __restrict__ bfv, const float* __restrict__ biv, const float* __restrict__ bdv,
    const float4* __restrict__ field,
    const ushort* __restrict__ Wt,
    float* __restrict__ out)
{
    const int tid  = threadIdx.x;
    const int lane = tid & 63;
    const int wave = tid >> 6;
    const int l15  = lane & 15;
    const int lg   = lane >> 4;

    // persistent weight fragments (registers)
    bf16x8 wf[3][2][4];
#pragma unroll
    for (int g = 0; g < 3; ++g)
#pragma unroll
        for (int s = 0; s < 2; ++s) {
            const int n = l15 + 16 * (wave + 4 * s);
#pragma unroll
            for (int ks = 0; ks < 4; ++ks)
                wf[g][s][ks] = *(const bf16x8*)(Wt + ((g * 128 + n) * 128 + 32 * ks + 8 * lg));
        }

    const int c0 = l15 + 16 * wave;
    const float bia[3][2] = { { bfv[c0] + 2.0f, bfv[c0 + 64] + 2.0f },
                              { biv[c0],        biv[c0 + 64]        },
                              { bdv[c0],        bdv[c0 + 64]        } };

    const int hw0 = blockIdx.x * PPB;

    // running per-thread pointers
    const float* ab = x + ((size_t)l15 * HW_TOTAL + hw0) * C2 + 8 * lg;   // A-frag rows
    const float* rbp[4];
    float* op[4];
#pragma unroll
    for (int r = 0; r < 4; ++r) {
        rbp[r] = x   + ((size_t)(4 * lg + r) * HW_TOTAL + hw0) * C2 + c0;
        op[r]  = out + ((size_t)(4 * lg + r) * HW_TOTAL + hw0) * C2 + c0;
    }
    const float4* fldp = field + (size_t)hw0 * 64 + c0;

    // double-banked register pipeline state (static names only)
    float4 rawA[8], rawB[8];
    float4 fldA, fldB;
    float  xrA[4], xiA[4], xrB[4], xiB[4];

    auto load_all = [&](float4 (&ra)[8], float4& fld, float (&xr)[4], float (&xi)[4]) {
#pragma unroll
        for (int ks = 0; ks < 4; ++ks) {
            ra[2 * ks]     = *(const float4*)(ab + 32 * ks);
            ra[2 * ks + 1] = *(const float4*)(ab + 32 * ks + 4);
        }
        ab += C2;
        fld = *fldp; fldp += 64;
#pragma unroll
        for (int r = 0; r < 4; ++r) {
            xr[r] = rbp[r][0];
            xi[r] = rbp[r][64];
            rbp[r] += C2;
        }
    };

    auto compute = [&](const float4 (&ra)[8], const float4& fld,
                       const float (&xr4)[4], const float (&xi4)[4]) {
        // convert A-tile to bf16 fragments
        bf16x8 af[4];
#pragma unroll
        for (int ks = 0; ks < 4; ++ks) {
            union { unsigned u[4]; bf16x8 v; } pk;
            pk.u[0] = pk2bf(ra[2 * ks].x,     ra[2 * ks].y);
            pk.u[1] = pk2bf(ra[2 * ks].z,     ra[2 * ks].w);
            pk.u[2] = pk2bf(ra[2 * ks + 1].x, ra[2 * ks + 1].y);
            pk.u[3] = pk2bf(ra[2 * ks + 1].z, ra[2 * ks + 1].w);
            af[ks] = pk.v;
        }

        // GEMM: 3 gates x 2 halves, K=128, bias in C-operand
        f32x4 acc[3][2];
#pragma unroll
        for (int g = 0; g < 3; ++g)
#pragma unroll
            for (int s = 0; s < 2; ++s) {
                const float b = bia[g][s];
                acc[g][s] = (f32x4){b, b, b, b};
            }
#pragma unroll
        for (int ks = 0; ks < 4; ++ks)
#pragma unroll
            for (int g = 0; g < 3; ++g)
#pragma unroll
                for (int s = 0; s < 2; ++s)
                    acc[g][s] = __builtin_amdgcn_mfma_f32_16x16x32_bf16(
                        af[ks], wf[g][s][ks], acc[g][s], 0, 0, 0);

        // gates + T=16 recurrence (matrix doubling); Br,Bi pre-scaled by 0.1
        const float Ar = fld.x, Ai = fld.y, Br = fld.z, Bi = fld.w;
#pragma unroll
        for (int r = 0; r < 4; ++r) {
            const float fg_r = fast_sigmoid(acc[0][0][r]);
            const float fg_i = fast_sigmoid(acc[0][1][r]);
            const float ig_r = fast_sigmoid(acc[1][0][r]);
            const float ig_i = fast_sigmoid(acc[1][1][r]);
            const float dl_r = fast_softplus(acc[2][0][r]);
            const float dl_i = fast_softplus(acc[2][1][r]);
            float vr = dl_r * ig_r * fmaf(Br, xr4[r], -Bi * xi4[r]);
            float vi = dl_i * ig_i * fmaf(Br, xi4[r],  Bi * xr4[r]);
            float a  = fg_r * Ar, bm = -(fg_r * Ai);
            float cm = fg_i * Ai, d  = fg_i * Ar;
#pragma unroll
            for (int j = 0; j < 4; ++j) {
                const float nvr = fmaf(a, vr, fmaf(bm, vi, vr));
                const float nvi = fmaf(cm, vr, fmaf(d, vi, vi));
                if (j < 3) {
                    const float trc = a + d, bc = bm * cm;
                    const float na = fmaf(a, a, bc), nd = fmaf(d, d, bc);
                    const float nb = bm * trc, nc = cm * trc;
                    a = na; bm = nb; cm = nc; d = nd;
                }
                vr = nvr; vi = nvi;
            }
            op[r][0]  = vr;
            op[r][64] = vi;
            op[r] += C2;
        }
    };

    // prologue: pixel 0 fully prefetched
    load_all(rawA, fldA, xrA, xiA);
    for (int p = 0; p < PPB; p += 2) {
        load_all(rawB, fldB, xrB, xiB);        // issue loads for p+1
        compute(rawA, fldA, xrA, xiA);         // compute pixel p
        if (p + 2 < PPB)
            load_all(rawA, fldA, xrA, xiA);    // issue loads for p+2
        compute(rawB, fldB, xrB, xiB);         // compute pixel p+1
    }
}

extern "C" void kernel_launch(void* const* d_in, const int* in_sizes, int n_in,
                              void* d_out, int out_size, void* d_ws, size_t ws_size,
                              hipStream_t stream) {
    const float* x      = (const float*)d_in[0];
    const float* Wf     = (const float*)d_in[1];
    const float* bf     = (const float*)d_in[2];
    const float* Wi     = (const float*)d_in[3];
    const float* bi     = (const float*)d_in[4];
    const float* Wd     = (const float*)d_in[5];
    const float* bd     = (const float*)d_in[6];
    const float* A_real = (const float*)d_in[7];
    const float* A_imag = (const float*)d_in[8];
    const float* B_real = (const float*)d_in[9];
    const float* B_imag = (const float*)d_in[10];

    float4* field = (float4*)d_ws;                                       // 16 MiB
    ushort* Wt = (ushort*)((char*)d_ws + (size_t)HW_TOTAL * 64 * 16);    // 96 KiB

    field_kernel<<<dim3(256), dim3(256), 0, stream>>>(A_real, A_imag, B_real, B_imag, field);
    wprep_kernel<<<dim3(192), dim3(256), 0, stream>>>(Wf, Wi, Wd, Wt);
    main_kernel<<<dim3(NBLK), dim3(256), 0, stream>>>(x, bf, bi, bd, field, Wt, (float*)d_out);
}

// Round 7
// 109.996 us; speedup vs baseline: 1.4277x; 1.3704x over previous
//
#include <hip/hip_runtime.h>
#include <hip/hip_bf16.h>

#define HW_TOTAL 16384
#define C2 128
#define PPB 16
#define NBLK (HW_TOTAL / PPB)

typedef short bf16x8 __attribute__((ext_vector_type(8)));
typedef float f32x4 __attribute__((ext_vector_type(4)));

__device__ __forceinline__ unsigned pk2bf(float lo, float hi) {
    __hip_bfloat162 h = __float22bfloat162_rn(make_float2(lo, hi));
    union { __hip_bfloat162 h; unsigned u; } v; v.h = h;
    return v.u;
}
__device__ __forceinline__ unsigned short f2bf(float f) {
    union { float f; unsigned u; } v; v.f = f;
    unsigned r = v.u + 0x7FFFu + ((v.u >> 16) & 1u);
    return (unsigned short)(r >> 16);
}
__device__ __forceinline__ float fast_sigmoid(float x) {
    return __builtin_amdgcn_rcpf(1.0f + __expf(-x));
}
__device__ __forceinline__ float fast_softplus(float x) {
    return fmaxf(x, 0.0f) + __logf(1.0f + __expf(-fabsf(x)));
}
// barrier WITHOUT vmcnt(0) drain: LDS is the only cross-thread medium here,
// so lgkmcnt(0)+s_barrier is sufficient; global loads/stores stay in flight.
__device__ __forceinline__ void block_sync_lds() {
    asm volatile("s_waitcnt lgkmcnt(0)\n\ts_barrier" ::: "memory");
}

// ---- Kernel 1: separable DFT of padded 7x7 kernels -> field[hw][c] = (Ar,Ai,0.1*Br,0.1*Bi) ----
__global__ void field_kernel(const float* __restrict__ Ark, const float* __restrict__ Aik,
                             const float* __restrict__ Brk, const float* __restrict__ Bik,
                             float4* __restrict__ field) {
    __shared__ float2 tw[128];
    __shared__ float2 G[2][64][9];
    const int v = blockIdx.x >> 1;
    const int uhalf = blockIdx.x & 1;
    const int t = threadIdx.x;
    if (t < 128) {
        float ph = (float)t * (6.283185307179586f / 128.0f);
        tw[t] = make_float2(cosf(ph), sinf(ph));
    }
    __syncthreads();
    for (int e = t; e < 896; e += 256) {
        const int kern = (e >= 448) ? 1 : 0;
        const int rem = e - kern * 448;
        const int c = rem / 7, p = rem % 7;
        const float* kr = kern ? Brk : Ark;
        const float* ki = kern ? Bik : Aik;
        float gr = 0.f, gi = 0.f;
#pragma unroll
        for (int q = 0; q < 7; ++q) {
            const int idx = (v * (q + 60)) & 127;
            const float twr = tw[idx].x, twi = -tw[idx].y;
            const float ar = kr[c * 49 + p * 7 + q], ai = ki[c * 49 + p * 7 + q];
            gr += ar * twr - ai * twi;
            gi += ar * twi + ai * twr;
        }
        G[kern][c][p] = make_float2(gr, gi);
    }
    __syncthreads();
    const int c = t & 63, ug = t >> 6;
    float2 gA[7], gB[7];
#pragma unroll
    for (int p = 0; p < 7; ++p) { gA[p] = G[0][c][p]; gB[p] = G[1][c][p]; }
    for (int k = 0; k < 16; ++k) {
        const int u = uhalf * 64 + ug * 16 + k;
        float Are = 0.f, Aim = 0.f, Bre = 0.f, Bim = 0.f;
#pragma unroll
        for (int p = 0; p < 7; ++p) {
            const int idx = (u * (p + 60)) & 127;
            const float twr = tw[idx].x, twi = -tw[idx].y;
            Are += gA[p].x * twr - gA[p].y * twi;
            Aim += gA[p].x * twi + gA[p].y * twr;
            Bre += gB[p].x * twr - gB[p].y * twi;
            Bim += gB[p].x * twi + gB[p].y * twr;
        }
        const float mag = sqrtf(Are * Are + Aim * Aim + 1e-8f);
        const float scale = 0.95f * (1.0f / (1.0f + expf(-mag))) / (mag + 1e-8f);
        field[(size_t)(u * 128 + v) * 64 + c] =
            make_float4(Are * scale, Aim * scale, Bre * 0.1f, Bim * 0.1f);
    }
}

// ---- Kernel 2: weights fp32 (k,n) -> bf16 transposed (g,n,k) ----
__global__ void wprep_kernel(const float* __restrict__ Wf, const float* __restrict__ Wi,
                             const float* __restrict__ Wd, ushort* __restrict__ Wt) {
    const int idx = blockIdx.x * 256 + threadIdx.x;
    const int g = idx >> 14;
    const int r = idx & 16383;
    const int n = r >> 7, k = r & 127;
    const float* W = (g == 0) ? Wf : (g == 1) ? Wi : Wd;
    Wt[idx] = f2bf(W[k * 128 + n]);
}

// ---- Kernel 3: LDS-staged pipeline, lgkm-only barriers, 2-deep prefetch ----
__global__ __launch_bounds__(256, 2) void main_kernel(
    const float* __restrict__ x,
    const float* __restrict__ bfv, const float* __restrict__ biv, const float* __restrict__ bdv,
    const float4* __restrict__ field,
    const ushort* __restrict__ Wt,
    float* __restrict__ out)
{
    __shared__ float  xsf[2][16][132];   // fp32 tile (recurrence inputs)
    __shared__ ushort xsb[2][16][136];   // bf16 tile (MFMA A-frags)
    const int tid  = threadIdx.x;
    const int lane = tid & 63;
    const int wave = tid >> 6;
    const int l15  = lane & 15;
    const int lg   = lane >> 4;

    // persistent weight fragments
    bf16x8 wf[3][2][4];
#pragma unroll
    for (int g = 0; g < 3; ++g)
#pragma unroll
        for (int s = 0; s < 2; ++s) {
            const int n = l15 + 16 * (wave + 4 * s);
#pragma unroll
            for (int ks = 0; ks < 4; ++ks)
                wf[g][s][ks] = *(const bf16x8*)(Wt + ((g * 128 + n) * 128 + 32 * ks + 8 * lg));
        }

    const int c0 = l15 + 16 * wave;
    const float bia[3][2] = { { bfv[c0] + 2.0f, bfv[c0 + 64] + 2.0f },
                              { biv[c0],        biv[c0 + 64]        },
                              { bdv[c0],        bdv[c0 + 64]        } };

    const int srow = tid >> 4;
    const int scol = (tid & 15) * 8;
    const int hw0 = blockIdx.x * PPB;

    const float* srcp = x + ((size_t)srow * HW_TOTAL + hw0) * C2 + scol;
    const float4* fldp = field + (size_t)hw0 * 64 + c0;
    float* op[4];
#pragma unroll
    for (int r = 0; r < 4; ++r)
        op[r] = out + ((size_t)(4 * lg + r) * HW_TOTAL + hw0) * C2 + c0;

    float4 qaA, qbA, qaB, qbB;   // tile prefetch banks (2-deep)
    float4 fldA, fldB;           // field prefetch banks

    auto stage = [&](float (*wbF)[132], ushort (*wbB)[136], const float4& qa, const float4& qb) {
        *(float4*)&wbF[srow][scol]     = qa;
        *(float4*)&wbF[srow][scol + 4] = qb;
        unsigned pk[4] = { pk2bf(qa.x, qa.y), pk2bf(qa.z, qa.w),
                           pk2bf(qb.x, qb.y), pk2bf(qb.z, qb.w) };
        *(uint4*)&wbB[srow][scol] = *(uint4*)pk;
    };

    auto body = [&](int p, const float (*rbF)[132], const ushort (*rbB)[136],
                    float (*wbF)[132], ushort (*wbB)[136],
                    float4& qa, float4& qb, float4& fldbank) {
        // 1. LDS reads for pixel p (latency covered by stage+issue below)
        bf16x8 af[4];
#pragma unroll
        for (int ks = 0; ks < 4; ++ks)
            af[ks] = *(const bf16x8*)&rbB[l15][8 * lg + 32 * ks];
        float xr4[4], xi4[4];
#pragma unroll
        for (int r = 0; r < 4; ++r) {
            xr4[r] = rbF[4 * lg + r][c0];
            xi4[r] = rbF[4 * lg + r][c0 + 64];
        }

        // 2. stage pixel p+1 (data loaded 2 bodies ago -> no vmcnt stall)
        if (p + 1 < PPB) stage(wbF, wbB, qa, qb);

        // 3. issue loads for pixel p+3 tile / p+2 field into the freed banks
        if (p + 3 < PPB) {
            qa = *(const float4*)srcp;
            qb = *(const float4*)(srcp + 4);
            srcp += C2;
        }
        const float4 fld = fldbank;
        if (p + 2 < PPB) { fldbank = *fldp; fldp += 64; }

        // 4. GEMM: 3 gates x 2 halves, K=128, bias in C-operand
        f32x4 acc[3][2];
#pragma unroll
        for (int g = 0; g < 3; ++g)
#pragma unroll
            for (int s = 0; s < 2; ++s) {
                const float b = bia[g][s];
                acc[g][s] = (f32x4){b, b, b, b};
            }
#pragma unroll
        for (int ks = 0; ks < 4; ++ks)
#pragma unroll
            for (int g = 0; g < 3; ++g)
#pragma unroll
                for (int s = 0; s < 2; ++s)
                    acc[g][s] = __builtin_amdgcn_mfma_f32_16x16x32_bf16(
                        af[ks], wf[g][s][ks], acc[g][s], 0, 0, 0);

        // 5. gates + T=16 recurrence (matrix doubling); Br,Bi pre-scaled by 0.1
        const float Ar = fld.x, Ai = fld.y, Br = fld.z, Bi = fld.w;
#pragma unroll
        for (int r = 0; r < 4; ++r) {
            const float fg_r = fast_sigmoid(acc[0][0][r]);
            const float fg_i = fast_sigmoid(acc[0][1][r]);
            const float ig_r = fast_sigmoid(acc[1][0][r]);
            const float ig_i = fast_sigmoid(acc[1][1][r]);
            const float dl_r = fast_softplus(acc[2][0][r]);
            const float dl_i = fast_softplus(acc[2][1][r]);
            float vr = dl_r * ig_r * fmaf(Br, xr4[r], -Bi * xi4[r]);
            float vi = dl_i * ig_i * fmaf(Br, xi4[r],  Bi * xr4[r]);
            float a  = fg_r * Ar, bm = -(fg_r * Ai);
            float cm = fg_i * Ai, d  = fg_i * Ar;
#pragma unroll
            for (int j = 0; j < 4; ++j) {
                const float nvr = fmaf(a, vr, fmaf(bm, vi, vr));
                const float nvi = fmaf(cm, vr, fmaf(d, vi, vi));
                if (j < 3) {
                    const float trc = a + d, bc = bm * cm;
                    const float na = fmaf(a, a, bc), nd = fmaf(d, d, bc);
                    const float nb = bm * trc, nc = cm * trc;
                    a = na; bm = nb; cm = nc; d = nd;
                }
                vr = nvr; vi = nvi;
            }
            op[r][0]  = vr;
            op[r][64] = vi;
            op[r] += C2;
        }

        // 6. barrier: LDS-only drain (stores/loads stay in flight)
        block_sync_lds();
    };

    // prologue: stage tile(0); prefetch tiles 1,2 and fields 0,1
    {
        float4 q0a = *(const float4*)srcp;
        float4 q0b = *(const float4*)(srcp + 4);
        srcp += C2;
        stage(xsf[0], xsb[0], q0a, q0b);
    }
    qaA = *(const float4*)srcp; qbA = *(const float4*)(srcp + 4); srcp += C2;
    qaB = *(const float4*)srcp; qbB = *(const float4*)(srcp + 4); srcp += C2;
    fldA = *fldp; fldp += 64;
    fldB = *fldp; fldp += 64;
    block_sync_lds();

    for (int p = 0; p < PPB; p += 2) {
        body(p,     xsf[0], xsb[0], xsf[1], xsb[1], qaA, qbA, fldA);
        body(p + 1, xsf[1], xsb[1], xsf[0], xsb[0], qaB, qbB, fldB);
    }
}

extern "C" void kernel_launch(void* const* d_in, const int* in_sizes, int n_in,
                              void* d_out, int out_size, void* d_ws, size_t ws_size,
                              hipStream_t stream) {
    const float* x      = (const float*)d_in[0];
    const float* Wf     = (const float*)d_in[1];
    const float* bf     = (const float*)d_in[2];
    const float* Wi     = (const float*)d_in[3];
    const float* bi     = (const float*)d_in[4];
    const float* Wd     = (const float*)d_in[5];
    const float* bd     = (const float*)d_in[6];
    const float* A_real = (const float*)d_in[7];
    const float* A_imag = (const float*)d_in[8];
    const float* B_real = (const float*)d_in[9];
    const float* B_imag = (const float*)d_in[10];

    float4* field = (float4*)d_ws;                                       // 16 MiB
    ushort* Wt = (ushort*)((char*)d_ws + (size_t)HW_TOTAL * 64 * 16);    // 96 KiB

    field_kernel<<<dim3(256), dim3(256), 0, stream>>>(A_real, A_imag, B_real, B_imag, field);
    wprep_kernel<<<dim3(192), dim3(256), 0, stream>>>(Wf, Wi, Wd, Wt);
    main_kernel<<<dim3(NBLK), dim3(256), 0, stream>>>(x, bf, bi, bd, field, Wt, (float*)d_out);
}